// Round 1
// baseline (102.569 us; speedup 1.0000x reference)
//
#include <hip/hip_runtime.h>
#include <stdint.h>

// Problem constants (match reference setup_inputs)
namespace {
constexpr int B = 4, P = 4, V = 4096, M = 2048;
constexpr int BP = B * P;
constexpr float BIGF = 1e10f;
constexpr int TPB   = 256;          // 4 waves per chamfer block
constexpr int OTILE = 128;          // outer points per block (2 per lane)
constexpr int XT = V / OTILE;       // 32 x-role outer tiles
constexpr int YT = M / OTILE;       // 16 y-role outer tiles
constexpr int ROLES = XT + YT;      // 48
constexpr int NBLK = BP * ROLES;    // 768 chamfer blocks (all increment counter)
constexpr int UN = 8;               // inner unroll (8 uniform dwordx4 in flight)
constexpr int KPB = 4;              // prep blocks per (b,p)
constexpr int VPB = V / KPB;        // 1024 vertices per prep block
constexpr int MPB = M / KPB;        // 512 edgemap elems per prep block
}

// workspace offsets (bytes)
//   0    nvalid (16 int)
//   64   sx     (16 float)
//   128  sy     (16 float)
//   192  done counter (1 int)
//   256  pnk (BP*V float4)  packed (x, y, |p|^2, 0) compacted projected pts
//   then epk (BP*M float4)  packed (x, y, |e|^2, 0) edge points

// ---------------------------------------------------------------------------
// prep: 4 blocks per (b,p). Each block detects the mask layout, popcounts the
// mask prefix of earlier chunks to get its deterministic compaction base (no
// cross-block atomics), projects+compacts its 1024 vertices, packs its 512
// edgemap elems with norms. Last chunk-block writes nvalid; chunk-0 blocks
// zero the accumulators.  grid = BP*KPB blocks, 256 threads.
// ---------------------------------------------------------------------------
__global__ __launch_bounds__(256) void prep_kernel(
    const float* __restrict__ vertices,    // (B,V,3)
    const float* __restrict__ projmats,    // (P,3,4)
    const uint8_t* __restrict__ maskraw,   // (B,P,V) unknown elem layout
    const float* __restrict__ edgemaps,    // (B,P,M,2)
    int* __restrict__ nvalid,
    float* __restrict__ sx,
    float* __restrict__ sy,
    int* __restrict__ done,
    float4* __restrict__ pnk,              // (BP,V)
    float4* __restrict__ epk)              // (BP,M)
{
    const int bp = blockIdx.x / KPB;
    const int k  = blockIdx.x % KPB;
    const int b = bp / P, p = bp % P;
    const int tid = threadIdx.x;
    const int lane = tid & 63;
    const int wave = tid >> 6;

    __shared__ int s_res[4];
    __shared__ int s_cnt;
    __shared__ int s_prew[4];
    if (tid < 4) { s_res[tid] = 0; s_prew[tid] = 0; }
    if (tid == 0) s_cnt = 0;
    __syncthreads();

    // --- detect mask element layout by byte-residue pattern (mod 4) ---
    // uint8 bernoulli(0.3): nonzero bytes at every residue.
    // int32 0/1 (LE):       nonzero only at residue 0.
    // float32 0/1.0f (LE):  nonzero only at residues 2 (0x80) and 3 (0x3f).
    uint32_t loc[4] = {0u, 0u, 0u, 0u};
    const int NB = 16384;   // 16 KiB prefix: >=4096 elems under every layout
    for (int i = tid * 16; i < NB; i += 256 * 16) {
        const uint32_t* w = (const uint32_t*)(maskraw + i);
        const uint32_t orw = w[0] | w[1] | w[2] | w[3];
        loc[0] |= orw & 0x000000FFu;
        loc[1] |= orw & 0x0000FF00u;
        loc[2] |= orw & 0x00FF0000u;
        loc[3] |= orw & 0xFF000000u;
    }
    #pragma unroll
    for (int j = 0; j < 4; ++j)
        if (loc[j]) atomicOr(&s_res[j], 1);
    __syncthreads();
    int layout;  // 0 = uint8/bool, 1 = int32, 2 = float32
    if (!s_res[1] && !s_res[2] && !s_res[3]) layout = 1;
    else if (!s_res[0] && !s_res[1])         layout = 2;
    else                                      layout = 0;

    // --- pack my edgemap quarter with norms ---
    {
        const float2* eg = (const float2*)edgemaps + (size_t)bp * M;
        for (int m = k * MPB + tid; m < (k + 1) * MPB; m += 256) {
            const float2 e = eg[m];
            epk[(size_t)bp * M + m] =
                make_float4(e.x, e.y, fmaf(e.x, e.x, e.y * e.y), 0.f);
        }
    }

    // --- popcount mask prefix [0, k*VPB) -> deterministic compaction base ---
    const int pre_n = k * VPB;
    int cnt = 0;
    if (layout == 0) {
        const uint8_t* mk = maskraw + (size_t)bp * V;
        for (int i = tid; i < pre_n; i += 256) cnt += (mk[i] != 0);
    } else if (layout == 1) {
        const int* mk = (const int*)maskraw + (size_t)bp * V;
        for (int i = tid; i < pre_n; i += 256) cnt += (mk[i] != 0);
    } else {
        const float* mk = (const float*)maskraw + (size_t)bp * V;
        for (int i = tid; i < pre_n; i += 256) cnt += (mk[i] != 0.0f);
    }
    #pragma unroll
    for (int off = 32; off > 0; off >>= 1) cnt += __shfl_down(cnt, off, 64);
    if (lane == 0) s_prew[wave] = cnt;
    __syncthreads();
    const int pre_total = s_prew[0] + s_prew[1] + s_prew[2] + s_prew[3];

    // --- projection matrix for this view (uniform per block) ---
    float mm[12];
    #pragma unroll
    for (int j = 0; j < 12; ++j) mm[j] = projmats[p * 12 + j];

    // --- project + compact my 1024 vertices (ballot-prefix compaction) ---
    for (int v = k * VPB + tid; v < (k + 1) * VPB; v += 256) {
        const int mi = bp * V + v;
        bool msk;
        if (layout == 0)      msk = maskraw[mi] != 0;
        else if (layout == 1) msk = ((const int*)maskraw)[mi] != 0;
        else                  msk = ((const float*)maskraw)[mi] != 0.0f;

        const unsigned long long ball = __ballot(msk);
        const int bcnt = __popcll(ball);
        int base = 0;
        if (lane == 0 && bcnt) base = atomicAdd(&s_cnt, bcnt);
        base = __shfl(base, 0, 64);
        if (msk) {
            const float x = vertices[(b * V + v) * 3 + 0];
            const float y = vertices[(b * V + v) * 3 + 1];
            const float z = vertices[(b * V + v) * 3 + 2];
            const float u  = mm[0]*x + mm[1]*y + mm[2]*z  + mm[3];
            const float vv = mm[4]*x + mm[5]*y + mm[6]*z  + mm[7];
            const float w  = mm[8]*x + mm[9]*y + mm[10]*z + mm[11];
            const int off = __popcll(ball & ((1ull << lane) - 1ull));
            const float rw = 1.0f / w;
            const float px = u * rw, py = vv * rw;
            pnk[(size_t)bp * V + pre_total + base + off] =
                make_float4(px, py, fmaf(px, px, py * py), 0.f);
        }
    }
    __syncthreads();
    if (tid == 0) {
        if (k == KPB - 1) nvalid[bp] = pre_total + s_cnt;
        if (k == 0) { sx[bp] = 0.0f; sy[bp] = 0.0f; }
        if (blockIdx.x == 0) *done = 0;
    }
}

// ---------------------------------------------------------------------------
// chamfer (fused finalize): block owns 128 outer points; its 4 waves split
// the inner range.  v2: NO LDS staging — each wave's inner quarter is
// wave-private and read exactly once, so the global->LDS->reg round trip was
// pure double-handling and made the hot loop LDS-pipe-bound (4 waves x
// uniform ds_read_b128 ~12cyc each vs 12cyc VALU).  Instead: direct
// uniform-address global_load_dwordx4, unrolled x8 (pnk+epk = 1.5 MB, fully
// L2/LLC resident; broadcast coalesces to one transaction).  Frees 32 KiB
// LDS/block -> occupancy 4 -> 8 blocks/CU.  Partial mins merged via 2 KiB
// LDS, one atomicAdd per block.  Last block (done counter) computes out[b].
// grid = (BP, ROLES), 256 threads.
// ---------------------------------------------------------------------------
__global__ __launch_bounds__(TPB) void chamfer_kernel(
    const int* __restrict__ elen,          // (B,P)
    int* __restrict__ nvalid,
    float* __restrict__ sx,
    float* __restrict__ sy,
    int* __restrict__ done,
    const float4* __restrict__ pnk,        // (BP,V)
    const float4* __restrict__ epk,        // (BP,M)
    float* __restrict__ out)               // (B)
{
    const int bp   = blockIdx.x;
    const int role = blockIdx.y;
    const int tid  = threadIdx.x;
    const int wave = tid >> 6;
    const int lane = tid & 63;
    const int len  = elen[bp];
    const int nv   = nvalid[bp];

    __shared__ float  smin[4][OTILE];  // 2 KiB merge buffer
    __shared__ int    s_last;

    const float4* outer; const float4* inner;
    int lim, L, obase;
    float* acc;
    const bool isX = (role < XT);
    if (isX) {
        obase = role * OTILE;
        outer = pnk + (size_t)bp * V;  lim = nv;
        inner = epk + (size_t)bp * M;  L = len;
        acc = &sx[bp];
    } else {
        obase = (role - XT) * OTILE;
        outer = epk + (size_t)bp * M;  lim = len;
        inner = pnk + (size_t)bp * V;  L = nv;
        acc = &sy[bp];
    }
    const bool active = (obase < lim);   // block-uniform

    float pn0 = 0.f, pn1 = 0.f;
    if (active) {
        // my 2 outer points (same set for all 4 waves)
        const float4 p0 = outer[obase + lane];
        const float4 p1 = outer[obase + 64 + lane];
        const float a0 = -2.0f * p0.x, b0 = -2.0f * p0.y;  pn0 = p0.z;
        const float a1 = -2.0f * p1.x, b1 = -2.0f * p1.y;  pn1 = p1.z;

        // wave-private inner range [is,ie) — read straight from global.
        const int q = (L + 3) >> 2;
        const int is = wave * q;
        const int ie = min(is + q, L);

        float mn0 = BIGF, mn1 = BIGF;
        int j = is;
        for (; j + UN <= ie; j += UN) {
            float4 t[UN];
            #pragma unroll
            for (int u = 0; u < UN; ++u) t[u] = inner[j + u];  // uniform addr
            #pragma unroll
            for (int u = 0; u < UN; ++u) {
                mn0 = fminf(mn0, fmaf(t[u].x, a0, fmaf(t[u].y, b0, t[u].z)));
                mn1 = fminf(mn1, fmaf(t[u].x, a1, fmaf(t[u].y, b1, t[u].z)));
            }
        }
        for (; j < ie; ++j) {
            const float4 t = inner[j];
            mn0 = fminf(mn0, fmaf(t.x, a0, fmaf(t.y, b0, t.z)));
            mn1 = fminf(mn1, fmaf(t.x, a1, fmaf(t.y, b1, t.z)));
        }
        smin[wave][lane]      = mn0;
        smin[wave][64 + lane] = mn1;
    }
    __syncthreads();                       // 'active' is block-uniform
    if (active && wave == 0) {
        const float m0 = fminf(fminf(smin[0][lane],      smin[1][lane]),
                               fminf(smin[2][lane],      smin[3][lane]));
        const float m1 = fminf(fminf(smin[0][64 + lane], smin[1][64 + lane]),
                               fminf(smin[2][64 + lane], smin[3][64 + lane]));
        float val = 0.0f;
        if (obase + lane < lim)      val += fmaxf(m0 + pn0, 0.0f);
        if (obase + 64 + lane < lim) val += fmaxf(m1 + pn1, 0.0f);
        #pragma unroll
        for (int off = 32; off > 0; off >>= 1)
            val += __shfl_down(val, off, 64);
        if (lane == 0) atomicAdd(acc, val);
    }

    // done-counter: every block increments exactly once; last block finalizes
    __syncthreads();
    if (tid == 0) {
        __threadfence();                               // release our adds
        const int old = atomicAdd(done, 1);
        s_last = (old == NBLK - 1) ? 1 : 0;
    }
    __syncthreads();
    if (s_last) {
        __threadfence();                               // acquire others' adds
        if (tid < B) {
            float o = 0.0f;
            #pragma unroll
            for (int p = 0; p < P; ++p) {
                const int j = tid * P + p;
                o += sx[j] / fmaxf((float)nvalid[j], 1.0f)
                   + sy[j] / fmaxf((float)elen[j], 1.0f);
            }
            out[tid] = o * (1.0f / P);
        }
    }
}

extern "C" void kernel_launch(void* const* d_in, const int* in_sizes, int n_in,
                              void* d_out, int out_size, void* d_ws, size_t ws_size,
                              hipStream_t stream)
{
    const float*   vertices = (const float*)d_in[0];
    const float*   projmats = (const float*)d_in[1];
    const float*   edgemaps = (const float*)d_in[2];
    const uint8_t* maskraw  = (const uint8_t*)d_in[3];
    const int*     elen     = (const int*)d_in[4];
    float* out = (float*)d_out;

    char* ws = (char*)d_ws;
    int*    nvalid = (int*)(ws + 0);
    float*  sx     = (float*)(ws + 64);
    float*  sy     = (float*)(ws + 128);
    int*    done   = (int*)(ws + 192);
    float4* pnk    = (float4*)(ws + 256);
    float4* epk    = pnk + (size_t)BP * V;

    prep_kernel<<<BP * KPB, 256, 0, stream>>>(vertices, projmats, maskraw,
                                              edgemaps, nvalid, sx, sy, done,
                                              pnk, epk);
    chamfer_kernel<<<dim3(BP, ROLES), TPB, 0, stream>>>(elen, nvalid, sx, sy,
                                                        done, pnk, epk, out);
}

// Round 2
// 101.900 us; speedup vs baseline: 1.0066x; 1.0066x over previous
//
#include <hip/hip_runtime.h>
#include <stdint.h>

// Problem constants (match reference setup_inputs)
namespace {
constexpr int B = 4, P = 4, V = 4096, M = 2048;
constexpr int BP = B * P;
constexpr float BIGF = 1e10f;
constexpr int TPB   = 256;          // 4 waves per chamfer block
constexpr int OTILE = 64;           // outer points per block (16 per wave)
constexpr int OPW   = 16;           // outers per wave (SGPR-broadcast)
constexpr int XT = V / OTILE;       // 64 x-role outer tiles
constexpr int YT = M / OTILE;       // 32 y-role outer tiles
constexpr int ROLES = XT + YT;      // 96
constexpr int NBLK = BP * ROLES;    // 1536 chamfer blocks (all bump counter)
constexpr int KPB = 8;              // prep blocks per (b,p)
constexpr int VPB = V / KPB;        // 512 vertices per prep block
constexpr int MPB = M / KPB;        // 256 edgemap elems per prep block
}

// workspace layout (bytes)
//   0    nvalid (16 int)
//   64   sx     (16 float)
//   128  sy     (16 float)
//   192  done counter (1 int)
//   256  pnk (BP*V float4)  inner form: ( x,  y, |p|^2)  compacted, padded
//   ...  epk (BP*M float4)  inner form: ( x,  y, |e|^2 or BIG beyond len)
//   ...  pnT (BP*V float4)  outer form: (-2x,-2y, |p|^2)  compacted
//   ...  epT (BP*M float4)  outer form: (-2x,-2y, |e|^2)

// ---------------------------------------------------------------------------
// prep: 8 blocks per (b,p). Detect mask layout, popcount mask prefix for a
// deterministic compaction base, project+compact 512 vertices (writing BOTH
// inner and outer forms), pack 256 edgemap elems (both forms; inner-form z
// masked to BIG beyond len so the chamfer hot loop is maskless). Last chunk
// block writes nvalid and pads pnk to a 128-multiple with (0,0,BIG).
// grid = BP*KPB = 128 blocks, 256 threads.
// ---------------------------------------------------------------------------
__global__ __launch_bounds__(256) void prep_kernel(
    const float* __restrict__ vertices,    // (B,V,3)
    const float* __restrict__ projmats,    // (P,3,4)
    const uint8_t* __restrict__ maskraw,   // (B,P,V) unknown elem layout
    const float* __restrict__ edgemaps,    // (B,P,M,2)
    const int* __restrict__ elen,          // (B,P)
    int* __restrict__ nvalid,
    float* __restrict__ sx,
    float* __restrict__ sy,
    int* __restrict__ done,
    float4* __restrict__ pnk,              // (BP,V) inner form
    float4* __restrict__ epk,              // (BP,M) inner form
    float4* __restrict__ pnT,              // (BP,V) outer form
    float4* __restrict__ epT)              // (BP,M) outer form
{
    const int bp = blockIdx.x / KPB;
    const int k  = blockIdx.x % KPB;
    const int b = bp / P, p = bp % P;
    const int tid = threadIdx.x;
    const int lane = tid & 63;
    const int wave = tid >> 6;

    __shared__ int s_res[4];
    __shared__ int s_cnt;
    __shared__ int s_prew[4];
    if (tid < 4) { s_res[tid] = 0; s_prew[tid] = 0; }
    if (tid == 0) s_cnt = 0;
    __syncthreads();

    // --- detect mask element layout by byte-residue pattern (mod 4) ---
    // uint8 bernoulli(0.3): nonzero bytes at every residue.
    // int32 0/1 (LE):       nonzero only at residue 0.
    // float32 0/1.0f (LE):  nonzero only at residues 2 (0x80) and 3 (0x3f).
    uint32_t loc[4] = {0u, 0u, 0u, 0u};
    const int NB = 16384;   // 16 KiB prefix: >=4096 elems under every layout
    for (int i = tid * 16; i < NB; i += 256 * 16) {
        const uint32_t* w = (const uint32_t*)(maskraw + i);
        const uint32_t orw = w[0] | w[1] | w[2] | w[3];
        loc[0] |= orw & 0x000000FFu;
        loc[1] |= orw & 0x0000FF00u;
        loc[2] |= orw & 0x00FF0000u;
        loc[3] |= orw & 0xFF000000u;
    }
    #pragma unroll
    for (int j = 0; j < 4; ++j)
        if (loc[j]) atomicOr(&s_res[j], 1);
    __syncthreads();
    int layout;  // 0 = uint8/bool, 1 = int32, 2 = float32
    if (!s_res[1] && !s_res[2] && !s_res[3]) layout = 1;
    else if (!s_res[0] && !s_res[1])         layout = 2;
    else                                      layout = 0;

    const int len = elen[bp];

    // --- pack my edgemap slice, both forms; inner z masked beyond len ---
    {
        const float2* eg = (const float2*)edgemaps + (size_t)bp * M;
        for (int m = k * MPB + tid; m < (k + 1) * MPB; m += 256) {
            const float2 e = eg[m];
            const float n = fmaf(e.x, e.x, e.y * e.y);
            epk[(size_t)bp * M + m] =
                make_float4(e.x, e.y, (m < len) ? n : BIGF, 0.f);
            epT[(size_t)bp * M + m] =
                make_float4(-2.0f * e.x, -2.0f * e.y, n, 0.f);
        }
    }

    // --- popcount mask prefix [0, k*VPB) -> deterministic compaction base ---
    const int pre_n = k * VPB;
    int cnt = 0;
    if (layout == 0) {
        const uint8_t* mk = maskraw + (size_t)bp * V;
        for (int i = tid; i < pre_n; i += 256) cnt += (mk[i] != 0);
    } else if (layout == 1) {
        const int* mk = (const int*)maskraw + (size_t)bp * V;
        for (int i = tid; i < pre_n; i += 256) cnt += (mk[i] != 0);
    } else {
        const float* mk = (const float*)maskraw + (size_t)bp * V;
        for (int i = tid; i < pre_n; i += 256) cnt += (mk[i] != 0.0f);
    }
    #pragma unroll
    for (int off = 32; off > 0; off >>= 1) cnt += __shfl_down(cnt, off, 64);
    if (lane == 0) s_prew[wave] = cnt;
    __syncthreads();
    const int pre_total = s_prew[0] + s_prew[1] + s_prew[2] + s_prew[3];

    // --- projection matrix for this view (uniform per block) ---
    float mm[12];
    #pragma unroll
    for (int j = 0; j < 12; ++j) mm[j] = projmats[p * 12 + j];

    // --- project + compact my vertices (ballot-prefix compaction) ---
    for (int v = k * VPB + tid; v < (k + 1) * VPB; v += 256) {
        const int mi = bp * V + v;
        bool msk;
        if (layout == 0)      msk = maskraw[mi] != 0;
        else if (layout == 1) msk = ((const int*)maskraw)[mi] != 0;
        else                  msk = ((const float*)maskraw)[mi] != 0.0f;

        const unsigned long long ball = __ballot(msk);
        const int bcnt = __popcll(ball);
        int base = 0;
        if (lane == 0 && bcnt) base = atomicAdd(&s_cnt, bcnt);
        base = __shfl(base, 0, 64);
        if (msk) {
            const float x = vertices[(b * V + v) * 3 + 0];
            const float y = vertices[(b * V + v) * 3 + 1];
            const float z = vertices[(b * V + v) * 3 + 2];
            const float u  = mm[0]*x + mm[1]*y + mm[2]*z  + mm[3];
            const float vv = mm[4]*x + mm[5]*y + mm[6]*z  + mm[7];
            const float w  = mm[8]*x + mm[9]*y + mm[10]*z + mm[11];
            const int off = __popcll(ball & ((1ull << lane) - 1ull));
            const float rw = 1.0f / w;
            const float px = u * rw, py = vv * rw;
            const float n  = fmaf(px, px, py * py);
            const size_t dst = (size_t)bp * V + pre_total + base + off;
            pnk[dst] = make_float4(px, py, n, 0.f);
            pnT[dst] = make_float4(-2.0f * px, -2.0f * py, n, 0.f);
        }
    }
    __syncthreads();
    if (k == KPB - 1) {
        const int nvv  = pre_total + s_cnt;
        const int npad = (nvv + 127) & ~127;           // <= V always
        for (int i = nvv + tid; i < npad; i += 256)
            pnk[(size_t)bp * V + i] = make_float4(0.f, 0.f, BIGF, 0.f);
        if (tid == 0) nvalid[bp] = nvv;
    }
    if (tid == 0) {
        if (k == 0) { sx[bp] = 0.0f; sy[bp] = 0.0f; }
        if (blockIdx.x == 0) *done = 0;
    }
}

// ---------------------------------------------------------------------------
// chamfer v3 (transposed): block owns 64 outer points; wave w owns 16 of
// them as wave-uniform scalars (readlane -> SGPR), and every wave scans the
// FULL inner range with per-lane coalesced global_load_dwordx4 (1 VMEM inst
// per 64 elems per wave; stream is L1/L2-resident and shared by the 4
// waves).  Hot loop is pure VALU, bit-identical per-pair arithmetic to the
// proven v1 form: fminf(mn, fmaf(t.x, -2px, fmaf(t.y, -2py, |e|^2))).
// Inner arrays are pre-padded to x128 with z=BIG so the loop is maskless.
// Block-end reduction via padded LDS transpose (2-way max bank aliasing =
// free).  OTILE=64 doubles the active-block count (~704 on 256 CUs) for
// better CU balance vs v1's 2-blocks-on-half-the-CUs skew.
// grid = (BP, ROLES), 256 threads.
// ---------------------------------------------------------------------------
__global__ __launch_bounds__(TPB) void chamfer_kernel(
    const int* __restrict__ elen,          // (B,P)
    int* __restrict__ nvalid,
    float* __restrict__ sx,
    float* __restrict__ sy,
    int* __restrict__ done,
    const float4* __restrict__ pnk,        // (BP,V) inner form
    const float4* __restrict__ epk,        // (BP,M) inner form
    const float4* __restrict__ pnT,        // (BP,V) outer form
    const float4* __restrict__ epT,        // (BP,M) outer form
    float* __restrict__ out)               // (B)
{
    const int bp   = blockIdx.x;
    const int role = blockIdx.y;
    const int tid  = threadIdx.x;
    const int wave = tid >> 6;
    const int lane = tid & 63;
    const int len  = elen[bp];
    const int nv   = nvalid[bp];

    __shared__ float sred[OTILE][65];   // padded: stride 65 -> 2-way max
    __shared__ float spart[OTILE][5];
    __shared__ int   s_last;

    const float4* outerT; const float4* inner;
    int lim, L, obase;
    float* acc;
    const bool isX = (role < XT);
    if (isX) {
        obase = role * OTILE;
        outerT = pnT + (size_t)bp * V;  lim = nv;
        inner  = epk + (size_t)bp * M;  L = len;
        acc = &sx[bp];
    } else {
        obase = (role - XT) * OTILE;
        outerT = epT + (size_t)bp * M;  lim = len;
        inner  = pnk + (size_t)bp * V;  L = nv;
        acc = &sy[bp];
    }
    const bool active = (obase < lim) && (L > 0);   // block-uniform

    if (active) {
        // wave's 16 outer points -> wave-uniform scalars (SGPRs).
        // lane l holds outer (wave*16 + (l&15)); readlane(o) reads lane o.
        const float4 op = outerT[obase + wave * OPW + (lane & (OPW - 1))];
        float sa[OPW], sb[OPW];
        #pragma unroll
        for (int o = 0; o < OPW; ++o) {
            sa[o] = __uint_as_float(
                __builtin_amdgcn_readlane(__float_as_uint(op.x), o));
            sb[o] = __uint_as_float(
                __builtin_amdgcn_readlane(__float_as_uint(op.y), o));
        }

        float mn[OPW];
        #pragma unroll
        for (int o = 0; o < OPW; ++o) mn[o] = BIGF;

        const int Lpad = (L + 127) & ~127;          // inner pre-padded
        float4 t0 = inner[lane];
        float4 t1 = inner[64 + lane];
        for (int c = 128; c < Lpad; c += 128) {
            const float4 n0 = inner[c + lane];       // prefetch next chunk
            const float4 n1 = inner[c + 64 + lane];
            #pragma unroll
            for (int o = 0; o < OPW; ++o)
                mn[o] = fminf(mn[o], fmaf(t0.x, sa[o], fmaf(t0.y, sb[o], t0.z)));
            #pragma unroll
            for (int o = 0; o < OPW; ++o)
                mn[o] = fminf(mn[o], fmaf(t1.x, sa[o], fmaf(t1.y, sb[o], t1.z)));
            t0 = n0; t1 = n1;
        }
        #pragma unroll
        for (int o = 0; o < OPW; ++o)
            mn[o] = fminf(mn[o], fmaf(t0.x, sa[o], fmaf(t0.y, sb[o], t0.z)));
        #pragma unroll
        for (int o = 0; o < OPW; ++o)
            mn[o] = fminf(mn[o], fmaf(t1.x, sa[o], fmaf(t1.y, sb[o], t1.z)));

        #pragma unroll
        for (int o = 0; o < OPW; ++o)
            sred[wave * OPW + o][lane] = mn[o];
    }
    __syncthreads();                       // 'active' is block-uniform
    if (active) {
        // 256 threads: thread -> (outer og = tid>>2, lane segment tid&3)
        const int og = tid >> 2, seg = tid & 3;
        float m = sred[og][seg * 16];
        #pragma unroll
        for (int i = 1; i < 16; ++i) m = fminf(m, sred[og][seg * 16 + i]);
        spart[og][seg] = m;
    }
    __syncthreads();
    if (active && wave == 0) {             // tid < 64
        const float m = fminf(fminf(spart[lane][0], spart[lane][1]),
                              fminf(spart[lane][2], spart[lane][3]));
        const float npv = outerT[obase + lane].z;   // |p|^2 of my outer
        float val = (obase + lane < lim) ? fmaxf(m + npv, 0.0f) : 0.0f;
        #pragma unroll
        for (int off = 32; off > 0; off >>= 1)
            val += __shfl_down(val, off, 64);
        if (lane == 0) atomicAdd(acc, val);
    }

    // done-counter: every block increments exactly once; last block finalizes
    __syncthreads();
    if (tid == 0) {
        __threadfence();                               // release our adds
        const int old = atomicAdd(done, 1);
        s_last = (old == NBLK - 1) ? 1 : 0;
    }
    __syncthreads();
    if (s_last) {
        __threadfence();                               // acquire others' adds
        if (tid < B) {
            float o = 0.0f;
            #pragma unroll
            for (int p = 0; p < P; ++p) {
                const int j = tid * P + p;
                o += sx[j] / fmaxf((float)nvalid[j], 1.0f)
                   + sy[j] / fmaxf((float)elen[j], 1.0f);
            }
            out[tid] = o * (1.0f / P);
        }
    }
}

extern "C" void kernel_launch(void* const* d_in, const int* in_sizes, int n_in,
                              void* d_out, int out_size, void* d_ws, size_t ws_size,
                              hipStream_t stream)
{
    const float*   vertices = (const float*)d_in[0];
    const float*   projmats = (const float*)d_in[1];
    const float*   edgemaps = (const float*)d_in[2];
    const uint8_t* maskraw  = (const uint8_t*)d_in[3];
    const int*     elen     = (const int*)d_in[4];
    float* out = (float*)d_out;

    char* ws = (char*)d_ws;
    int*    nvalid = (int*)(ws + 0);
    float*  sx     = (float*)(ws + 64);
    float*  sy     = (float*)(ws + 128);
    int*    done   = (int*)(ws + 192);
    float4* pnk    = (float4*)(ws + 256);
    float4* epk    = pnk + (size_t)BP * V;
    float4* pnT    = epk + (size_t)BP * M;
    float4* epT    = pnT + (size_t)BP * V;

    prep_kernel<<<BP * KPB, 256, 0, stream>>>(vertices, projmats, maskraw,
                                              edgemaps, elen, nvalid, sx, sy,
                                              done, pnk, epk, pnT, epT);
    chamfer_kernel<<<dim3(BP, ROLES), TPB, 0, stream>>>(elen, nvalid, sx, sy,
                                                        done, pnk, epk, pnT,
                                                        epT, out);
}

// Round 3
// 92.349 us; speedup vs baseline: 1.1107x; 1.1034x over previous
//
#include <hip/hip_runtime.h>
#include <stdint.h>

// Problem constants (match reference setup_inputs)
namespace {
constexpr int B = 4, P = 4, V = 4096, M = 2048;
constexpr int BP = B * P;
constexpr float BIGF = 1e10f;
constexpr int TPB   = 256;          // 4 waves per chamfer block (v1-proven)
constexpr int OTILE = 128;          // outer points per block (2 per lane)
constexpr int XT = V / OTILE;       // 32 x-role outer tiles
constexpr int YT = M / OTILE;       // 16 y-role outer tiles
constexpr int ROLES = XT + YT;      // 48 roles per bp
constexpr int CH = 512;             // inner elems staged per wave-chunk (8 KiB)
constexpr int KPB = 8;              // prep blocks per (b,p)
constexpr int VPB = V / KPB;        // 512 vertices per prep block
constexpr int MPB = M / KPB;        // 256 edgemap elems per prep block
}

// workspace offsets (bytes)
//   0    nvalid (16 int)
//   64   sx     (16 float)
//   128  sy     (16 float)
//   192  done   (16 int)   per-bp role counters (hierarchical finalize)
//   256  done2  (1 int)    bp-level counter
//   512  pnk (BP*V float4) packed (x, y, |p|^2, 0) compacted projected pts
//   then epk (BP*M float4) packed (x, y, |e|^2, 0) edge points

// ---------------------------------------------------------------------------
// prep: 8 blocks per (b,p). Each block detects the mask layout, popcounts the
// mask prefix of earlier chunks to get its deterministic compaction base (no
// cross-block atomics), projects+compacts its 512 vertices, packs its 256
// edgemap elems with norms. Last chunk-block writes nvalid; chunk-0 blocks
// zero the accumulators + per-bp done counter.  grid = BP*KPB = 128 blocks.
// ---------------------------------------------------------------------------
__global__ __launch_bounds__(256) void prep_kernel(
    const float* __restrict__ vertices,    // (B,V,3)
    const float* __restrict__ projmats,    // (P,3,4)
    const uint8_t* __restrict__ maskraw,   // (B,P,V) unknown elem layout
    const float* __restrict__ edgemaps,    // (B,P,M,2)
    int* __restrict__ nvalid,
    float* __restrict__ sx,
    float* __restrict__ sy,
    int* __restrict__ done,
    int* __restrict__ done2,
    float4* __restrict__ pnk,              // (BP,V)
    float4* __restrict__ epk)              // (BP,M)
{
    const int bp = blockIdx.x / KPB;
    const int k  = blockIdx.x % KPB;
    const int b = bp / P, p = bp % P;
    const int tid = threadIdx.x;
    const int lane = tid & 63;
    const int wave = tid >> 6;

    __shared__ int s_res[4];
    __shared__ int s_cnt;
    __shared__ int s_prew[4];
    if (tid < 4) { s_res[tid] = 0; s_prew[tid] = 0; }
    if (tid == 0) s_cnt = 0;
    __syncthreads();

    // --- detect mask element layout by byte-residue pattern (mod 4) ---
    // uint8 bernoulli(0.3): nonzero bytes at every residue.
    // int32 0/1 (LE):       nonzero only at residue 0.
    // float32 0/1.0f (LE):  nonzero only at residues 2 (0x80) and 3 (0x3f).
    uint32_t loc[4] = {0u, 0u, 0u, 0u};
    const int NB = 16384;   // 16 KiB prefix: >=4096 elems under every layout
    for (int i = tid * 16; i < NB; i += 256 * 16) {
        const uint32_t* w = (const uint32_t*)(maskraw + i);
        const uint32_t orw = w[0] | w[1] | w[2] | w[3];
        loc[0] |= orw & 0x000000FFu;
        loc[1] |= orw & 0x0000FF00u;
        loc[2] |= orw & 0x00FF0000u;
        loc[3] |= orw & 0xFF000000u;
    }
    #pragma unroll
    for (int j = 0; j < 4; ++j)
        if (loc[j]) atomicOr(&s_res[j], 1);
    __syncthreads();
    int layout;  // 0 = uint8/bool, 1 = int32, 2 = float32
    if (!s_res[1] && !s_res[2] && !s_res[3]) layout = 1;
    else if (!s_res[0] && !s_res[1])         layout = 2;
    else                                      layout = 0;

    // --- pack my edgemap slice with norms ---
    {
        const float2* eg = (const float2*)edgemaps + (size_t)bp * M;
        for (int m = k * MPB + tid; m < (k + 1) * MPB; m += 256) {
            const float2 e = eg[m];
            epk[(size_t)bp * M + m] =
                make_float4(e.x, e.y, fmaf(e.x, e.x, e.y * e.y), 0.f);
        }
    }

    // --- popcount mask prefix [0, k*VPB) -> deterministic compaction base ---
    const int pre_n = k * VPB;
    int cnt = 0;
    if (layout == 0) {
        const uint8_t* mk = maskraw + (size_t)bp * V;
        for (int i = tid; i < pre_n; i += 256) cnt += (mk[i] != 0);
    } else if (layout == 1) {
        const int* mk = (const int*)maskraw + (size_t)bp * V;
        for (int i = tid; i < pre_n; i += 256) cnt += (mk[i] != 0);
    } else {
        const float* mk = (const float*)maskraw + (size_t)bp * V;
        for (int i = tid; i < pre_n; i += 256) cnt += (mk[i] != 0.0f);
    }
    #pragma unroll
    for (int off = 32; off > 0; off >>= 1) cnt += __shfl_down(cnt, off, 64);
    if (lane == 0) s_prew[wave] = cnt;
    __syncthreads();
    const int pre_total = s_prew[0] + s_prew[1] + s_prew[2] + s_prew[3];

    // --- projection matrix for this view (uniform per block) ---
    float mm[12];
    #pragma unroll
    for (int j = 0; j < 12; ++j) mm[j] = projmats[p * 12 + j];

    // --- project + compact my 512 vertices (ballot-prefix compaction) ---
    for (int v = k * VPB + tid; v < (k + 1) * VPB; v += 256) {
        const int mi = bp * V + v;
        bool msk;
        if (layout == 0)      msk = maskraw[mi] != 0;
        else if (layout == 1) msk = ((const int*)maskraw)[mi] != 0;
        else                  msk = ((const float*)maskraw)[mi] != 0.0f;

        const unsigned long long ball = __ballot(msk);
        const int bcnt = __popcll(ball);
        int base = 0;
        if (lane == 0 && bcnt) base = atomicAdd(&s_cnt, bcnt);
        base = __shfl(base, 0, 64);
        if (msk) {
            const float x = vertices[(b * V + v) * 3 + 0];
            const float y = vertices[(b * V + v) * 3 + 1];
            const float z = vertices[(b * V + v) * 3 + 2];
            const float u  = mm[0]*x + mm[1]*y + mm[2]*z  + mm[3];
            const float vv = mm[4]*x + mm[5]*y + mm[6]*z  + mm[7];
            const float w  = mm[8]*x + mm[9]*y + mm[10]*z + mm[11];
            const int off = __popcll(ball & ((1ull << lane) - 1ull));
            const float rw = 1.0f / w;
            const float px = u * rw, py = vv * rw;
            pnk[(size_t)bp * V + pre_total + base + off] =
                make_float4(px, py, fmaf(px, px, py * py), 0.f);
        }
    }
    __syncthreads();
    if (tid == 0) {
        if (k == KPB - 1) nvalid[bp] = pre_total + s_cnt;
        if (k == 0) { sx[bp] = 0.0f; sy[bp] = 0.0f; done[bp] = 0; }
        if (blockIdx.x == 0) *done2 = 0;
    }
}

// ---------------------------------------------------------------------------
// chamfer (v1-proven hot path): block owns 128 outer points; its 4 waves
// split the inner range, each staging wave-local LDS chunks (no barriers in
// hot loop), d2 = (|e|^2 - 2e.p) + |p|^2 -> 3 VALU/pair/chain.  Partial
// mins merged via 2 KiB LDS, one atomicAdd per block.
// v4 deltas vs v1 (hot loop untouched):
//   - y-roles first: ~75%-active y blocks dispatch before the mostly-idle
//     x-tile tail -> active blocks cluster at the head of dispatch.
//   - hierarchical done: per-bp counter (16 addresses) + bp-level counter
//     replaces 768 same-address atomics.
// grid = (BP, ROLES), 256 threads.
// ---------------------------------------------------------------------------
__global__ __launch_bounds__(TPB) void chamfer_kernel(
    const int* __restrict__ elen,          // (B,P)
    int* __restrict__ nvalid,
    float* __restrict__ sx,
    float* __restrict__ sy,
    int* __restrict__ done,
    int* __restrict__ done2,
    const float4* __restrict__ pnk,        // (BP,V)
    const float4* __restrict__ epk,        // (BP,M)
    float* __restrict__ out)               // (B)
{
    const int bp   = blockIdx.x;
    const int role = blockIdx.y;
    const int tid  = threadIdx.x;
    const int wave = tid >> 6;
    const int lane = tid & 63;
    const int len  = elen[bp];
    const int nv   = nvalid[bp];

    __shared__ float4 sb[4][CH];       // 32 KiB wave-private staging
    __shared__ float  smin[4][OTILE];  // 2 KiB merge buffer
    __shared__ int    s_last;

    const float4* outer; const float4* inner;
    int lim, L, obase;
    float* acc;
    const bool isY = (role < YT);      // y-roles dispatched first
    if (isY) {
        obase = role * OTILE;
        outer = epk + (size_t)bp * M;  lim = len;
        inner = pnk + (size_t)bp * V;  L = nv;
        acc = &sy[bp];
    } else {
        obase = (role - YT) * OTILE;
        outer = pnk + (size_t)bp * V;  lim = nv;
        inner = epk + (size_t)bp * M;  L = len;
        acc = &sx[bp];
    }
    const bool active = (obase < lim);   // block-uniform

    float pn0 = 0.f, pn1 = 0.f;
    if (active) {
        // my 2 outer points (same set for all 4 waves)
        const float4 p0 = outer[obase + lane];
        const float4 p1 = outer[obase + 64 + lane];
        const float a0 = -2.0f * p0.x, b0 = -2.0f * p0.y;  pn0 = p0.z;
        const float a1 = -2.0f * p1.x, b1 = -2.0f * p1.y;  pn1 = p1.z;

        // wave-private inner range [s,e)
        const int q = (L + 3) >> 2;
        const int is = wave * q;
        const int ie = min(is + q, L);
        float4* sbw = sb[wave];

        float mn0 = BIGF, mn1 = BIGF;
        for (int cs = is; cs < ie; cs += CH) {
            const int cnt  = min(CH, ie - cs);
            const int cnt8 = (cnt + 7) & ~7;
            for (int j = lane; j < cnt; j += 64) sbw[j] = inner[cs + j];
            for (int j = cnt + lane; j < cnt8; j += 64)
                sbw[j] = make_float4(0.f, 0.f, BIGF, 0.f);   // exact no-op pad
            // wave-local RAW: compiler inserts lgkmcnt waits, no barrier
            #pragma unroll 8
            for (int j = 0; j < cnt8; ++j) {
                const float4 t = sbw[j];           // wave-uniform broadcast
                mn0 = fminf(mn0, fmaf(t.x, a0, fmaf(t.y, b0, t.z)));
                mn1 = fminf(mn1, fmaf(t.x, a1, fmaf(t.y, b1, t.z)));
            }
        }
        smin[wave][lane]      = mn0;
        smin[wave][64 + lane] = mn1;
    }
    __syncthreads();                       // 'active' is block-uniform
    if (active && wave == 0) {
        const float m0 = fminf(fminf(smin[0][lane],      smin[1][lane]),
                               fminf(smin[2][lane],      smin[3][lane]));
        const float m1 = fminf(fminf(smin[0][64 + lane], smin[1][64 + lane]),
                               fminf(smin[2][64 + lane], smin[3][64 + lane]));
        float val = 0.0f;
        if (obase + lane < lim)      val += fmaxf(m0 + pn0, 0.0f);
        if (obase + 64 + lane < lim) val += fmaxf(m1 + pn1, 0.0f);
        #pragma unroll
        for (int off = 32; off > 0; off >>= 1)
            val += __shfl_down(val, off, 64);
        if (lane == 0) atomicAdd(acc, val);
    }

    // hierarchical done: ROLES blocks per bp -> done[bp]; 16 bp -> done2.
    __syncthreads();
    if (tid == 0) {
        __threadfence();                               // release our adds
        int lastall = 0;
        const int old = atomicAdd(&done[bp], 1);
        if (old == ROLES - 1) {
            __threadfence();
            const int o2 = atomicAdd(done2, 1);
            lastall = (o2 == BP - 1) ? 1 : 0;
        }
        s_last = lastall;
    }
    __syncthreads();
    if (s_last) {
        __threadfence();                               // acquire others' adds
        if (tid < B) {
            float o = 0.0f;
            #pragma unroll
            for (int p = 0; p < P; ++p) {
                const int j = tid * P + p;
                o += sx[j] / fmaxf((float)nvalid[j], 1.0f)
                   + sy[j] / fmaxf((float)elen[j], 1.0f);
            }
            out[tid] = o * (1.0f / P);
        }
    }
}

extern "C" void kernel_launch(void* const* d_in, const int* in_sizes, int n_in,
                              void* d_out, int out_size, void* d_ws, size_t ws_size,
                              hipStream_t stream)
{
    const float*   vertices = (const float*)d_in[0];
    const float*   projmats = (const float*)d_in[1];
    const float*   edgemaps = (const float*)d_in[2];
    const uint8_t* maskraw  = (const uint8_t*)d_in[3];
    const int*     elen     = (const int*)d_in[4];
    float* out = (float*)d_out;

    char* ws = (char*)d_ws;
    int*    nvalid = (int*)(ws + 0);
    float*  sx     = (float*)(ws + 64);
    float*  sy     = (float*)(ws + 128);
    int*    done   = (int*)(ws + 192);
    int*    done2  = (int*)(ws + 256);
    float4* pnk    = (float4*)(ws + 512);
    float4* epk    = pnk + (size_t)BP * V;

    prep_kernel<<<BP * KPB, 256, 0, stream>>>(vertices, projmats, maskraw,
                                              edgemaps, nvalid, sx, sy, done,
                                              done2, pnk, epk);
    chamfer_kernel<<<dim3(BP, ROLES), TPB, 0, stream>>>(elen, nvalid, sx, sy,
                                                        done, done2, pnk, epk,
                                                        out);
}